// Round 1
// baseline (581.853 us; speedup 1.0000x reference)
//
#include <hip/hip_runtime.h>

#define N_NODES 100000
#define D 128
#define N_EDGES 640000
#define TOT_EDGES (3 * N_EDGES)   // 1,920,000

#define NB   256                  // buckets (node ranges)
#define NPB  391                  // nodes per bucket (256*391 >= 100000)
#define BCAP 9216                 // record capacity per bucket (mean 7500, +20 sigma)
#define OVF_CAP 16384
#define EPB  3072                 // edges per binA block
#define BINA_BLOCKS (TOT_EDGES / EPB)   // 625
#define EPT  (EPB / 256)                // 12 edges per thread
#define NKEY 2048                 // pow2 >= NPB*4 (local*4+set sort key space)

// ---------------- fast-path ws layout (bytes); total 60,515,016 ------------
#define WS_OVFCNT 0
#define WS_BCUR   64                         // int, stride 16 ints (64B/bucket)
#define WS_BBASE  16448                      // int[256]
#define WS_BNUM   17472                      // int[256]
#define WS_OVF    18496                      // int4[OVF_CAP], 256 KB
#define WS_TMP    280640                     // int2[NB*BCAP], 18.87 MB
#define WS_FREC   19155008                   // int2[TOT_EDGES], 15.36 MB
#define WS_OFFS   34515008                   // int[N_NODES+1]
#define WS_XB     34915016                   // ushort[N_NODES*D] bf16, 25.6 MB
#define WS_TOTAL_FAST 60515016

__device__ __forceinline__ void load_r(const float* z0, const float* z1,
                                       const float* z2, const float* z3,
                                       float& r0, float& r1, float& r2, float& r3) {
    r0 = fmaxf(z0[0], 0.0f);
    r1 = fmaxf(z1[0], 0.0f);
    r2 = fmaxf(z2[0], 0.0f);
    r3 = fmaxf(z3[0], 0.0f);
    float inv = 1.0f / (r0 + r1 + r2 + r3 + 1e-6f);
    r0 *= inv; r1 *= inv; r2 *= inv; r3 *= inv;
}

__device__ __forceinline__ unsigned short bf16rn(float f) {
    unsigned int u = __float_as_uint(f);
    u += 0x7FFFu + ((u >> 16) & 1u);   // round to nearest even
    return (unsigned short)(u >> 16);
}

// ---- cast x -> bf16 copy (halves gather traffic) ---------------------------
__global__ void cast_kernel(const float* __restrict__ x, ushort* __restrict__ xb) {
    int i = blockIdx.x * 256 + threadIdx.x;
    if (i >= N_NODES * D / 4) return;
    float4 v = ((const float4*)x)[i];
    ushort4 h;
    h.x = bf16rn(v.x); h.y = bf16rn(v.y); h.z = bf16rn(v.z); h.w = bf16rn(v.w);
    ((ushort4*)xb)[i] = h;
}

// ---------------------------------------------------------------------------
// binA: LDS-aggregated binning of all edges into 256 node-range buckets.
// Single pass over edge arrays (src read once); record built in registers.
// tmp rec: x = dst(17) | set<<17 (2) | local<<19 (9), y = f32 scale.
// ---------------------------------------------------------------------------
__global__ void binA_kernel(const int* __restrict__ ei1, const float* __restrict__ w1,
                            const int* __restrict__ ei2, const float* __restrict__ w2,
                            const int* __restrict__ ei3, const float* __restrict__ w3,
                            const float* __restrict__ z0, const float* __restrict__ z1,
                            const float* __restrict__ z2, const float* __restrict__ z3,
                            int* __restrict__ bcur, int* __restrict__ ovf_count,
                            int4* __restrict__ ovf, int2* __restrict__ tmp) {
    __shared__ int hist[NB];
    __shared__ int base[NB];
    int t = threadIdx.x;
    hist[t] = 0;
    __syncthreads();

    float r0, r1, r2, r3;
    load_r(z0, z1, z2, z3, r0, r1, r2, r3);

    int e0 = blockIdx.x * EPB;
    int rank[EPT];
    int bkt[EPT];
    int rxv[EPT];
    float scv[EPT];

#pragma unroll
    for (int k = 0; k < EPT; ++k) {
        int e = e0 + t + k * 256;
        int set = e / N_EDGES;
        int idx = e - set * N_EDGES;
        const int* ei;  const float* w;  float rk;
        if      (set == 0) { ei = ei1; w = w1; rk = r1; }
        else if (set == 1) { ei = ei2; w = w2; rk = r2; }
        else               { ei = ei3; w = w3; rk = r3; }
        int src = ei[idx];
        int dst = ei[N_EDGES + idx];
        int b = src / NPB;
        int local = src - b * NPB;
        bkt[k]  = b;
        rxv[k]  = dst | (set << 17) | (local << 19);
        scv[k]  = rk * w[idx];
        rank[k] = atomicAdd(&hist[b], 1);
    }
    __syncthreads();

    {
        int h = hist[t];
        base[t] = h ? atomicAdd(&bcur[t * 16], h) : 0;
    }
    __syncthreads();

#pragma unroll
    for (int k = 0; k < EPT; ++k) {
        int b = bkt[k];
        int pos = base[b] + rank[k];
        if (pos < BCAP) {
            tmp[(size_t)b * BCAP + pos] = make_int2(rxv[k], __float_as_int(scv[k]));
        } else {
            int o = atomicAdd(ovf_count, 1);
            int src = b * NPB + ((rxv[k] >> 19) & 0x1FF);
            if (o < OVF_CAP) ovf[o] = make_int4(src, rxv[k] & 0x7FFFF,
                                                __float_as_int(scv[k]), 0);
        }
    }
}

// scanB: exclusive scan of (clamped) bucket counts -> global bucket bases.
__global__ void scanB_kernel(const int* __restrict__ bcur,
                             int* __restrict__ bbase, int* __restrict__ bnum,
                             int* __restrict__ offsets) {
    __shared__ int s[NB];
    int t = threadIdx.x;
    int n = bcur[t * 16];
    if (n > BCAP) n = BCAP;
    bnum[t] = n;
    s[t] = n;
    __syncthreads();
    for (int off = 1; off < NB; off <<= 1) {
        int v = (t >= off) ? s[t - off] : 0;
        __syncthreads();
        s[t] += v;
        __syncthreads();
    }
    bbase[t] = s[t] - n;
    if (t == NB - 1) offsets[N_NODES] = s[t];
}

// binB: per-bucket local CSR via counting sort on key = local*4 + set.
// Set-grouping within each node keeps the gather's per-record shift
// wave-coherent under the 4-records-per-load scheme.
__global__ void binB_kernel(const int2* __restrict__ tmp,
                            const int* __restrict__ bbase, const int* __restrict__ bnum,
                            int2* __restrict__ frecs, int* __restrict__ offsets) {
    __shared__ int d[NKEY];
    __shared__ int ts[256];
    __shared__ int cur[NKEY];
    int b = blockIdx.x;
    int t = threadIdx.x;
    int n = bnum[b];
    int gbase = bbase[b];

    for (int i = t; i < NKEY; i += 256) d[i] = 0;
    __syncthreads();
    for (int i = t; i < n; i += 256) {
        int rx = tmp[(size_t)b * BCAP + i].x;
        int key = (((rx >> 19) & 0x1FF) << 2) | ((rx >> 17) & 3);
        atomicAdd(&d[key], 1);
    }
    __syncthreads();

    // scan: thread t owns keys 8t..8t+7 (serial) + 256-wide block scan
    int loc[8];
    int tot = 0;
#pragma unroll
    for (int k = 0; k < 8; ++k) { loc[k] = tot; tot += d[8 * t + k]; }
    ts[t] = tot;
    __syncthreads();
    for (int off = 1; off < 256; off <<= 1) {
        int v = (t >= off) ? ts[t - off] : 0;
        __syncthreads();
        ts[t] += v;
        __syncthreads();
    }
    int tbase = ts[t] - tot;
#pragma unroll
    for (int k = 0; k < 8; ++k) cur[8 * t + k] = tbase + loc[k];
    __syncthreads();

    int node0 = b * NPB;
    for (int l = t; l < NPB; l += 256) {
        int node = node0 + l;
        if (node < N_NODES) offsets[node] = gbase + cur[l << 2];
    }
    __syncthreads();

    for (int i = t; i < n; i += 256) {
        int2 rec = tmp[(size_t)b * BCAP + i];
        int key = (((rec.x >> 19) & 0x1FF) << 2) | ((rec.x >> 17) & 3);
        int pos = atomicAdd(&cur[key], 1);
        frecs[gbase + pos] = make_int2(rec.x & 0x7FFFF, rec.y);
    }
}

// ---------------------------------------------------------------------------
// gatherb v2: wave per node; 4 records per round, each row read by one lane
// quarter as uint4 (16B/lane -> 1 global_load_dwordx4 covers 4 rows).
// VMEM instr count ~4x lower than v1; bytes identical.
// ---------------------------------------------------------------------------
__device__ __forceinline__ void accum4(int rx, int ry, int l16,
                                       const ushort* __restrict__ xb,
                                       float4& a0lo, float4& a0hi,
                                       float4& a1lo, float4& a1hi,
                                       float4& a2lo, float4& a2hi) {
    const uint4* rowp = (const uint4*)(xb + (size_t)(rx & 0x1FFFF) * D);
    uint4 v = rowp[l16];
    int sh = (rx >> 17) & 3;
    float sc = __int_as_float(ry);
    float p0 = __uint_as_float(v.x << 16);
    float p1 = __uint_as_float(v.x & 0xFFFF0000u);
    float p2 = __uint_as_float(v.y << 16);
    float p3 = __uint_as_float(v.y & 0xFFFF0000u);
    float p4 = __uint_as_float(v.z << 16);
    float p5 = __uint_as_float(v.z & 0xFFFF0000u);
    float p6 = __uint_as_float(v.w << 16);
    float p7 = __uint_as_float(v.w & 0xFFFF0000u);
    if (sh == 0) {
        a0lo.x += sc * p0; a0lo.y += sc * p1; a0lo.z += sc * p2; a0lo.w += sc * p3;
        a0hi.x += sc * p4; a0hi.y += sc * p5; a0hi.z += sc * p6; a0hi.w += sc * p7;
    } else if (sh == 1) {
        a1lo.x += sc * p0; a1lo.y += sc * p1; a1lo.z += sc * p2; a1lo.w += sc * p3;
        a1hi.x += sc * p4; a1hi.y += sc * p5; a1hi.z += sc * p6; a1hi.w += sc * p7;
    } else {
        a2lo.x += sc * p0; a2lo.y += sc * p1; a2lo.z += sc * p2; a2lo.w += sc * p3;
        a2hi.x += sc * p4; a2hi.y += sc * p5; a2hi.z += sc * p6; a2hi.w += sc * p7;
    }
}

__device__ __forceinline__ void red4(float4& v) {
    v.x += __shfl_xor(v.x, 16); v.y += __shfl_xor(v.y, 16);
    v.z += __shfl_xor(v.z, 16); v.w += __shfl_xor(v.w, 16);
    v.x += __shfl_xor(v.x, 32); v.y += __shfl_xor(v.y, 32);
    v.z += __shfl_xor(v.z, 32); v.w += __shfl_xor(v.w, 32);
}

__global__ void gatherb_kernel(const float* __restrict__ x,
                               const ushort* __restrict__ xb,
                               const int* __restrict__ offsets,
                               const int2* __restrict__ recs,
                               const float* __restrict__ z0, const float* __restrict__ z1,
                               const float* __restrict__ z2, const float* __restrict__ z3,
                               float* __restrict__ out) {
    int wid  = (blockIdx.x * blockDim.x + threadIdx.x) >> 6;
    int lane = threadIdx.x & 63;
    if (wid >= N_NODES) return;

    float r0, r1, r2, r3;
    load_r(z0, z1, z2, z3, r0, r1, r2, r3);

    int qt  = lane >> 4;          // record slot within 4-group
    int l16 = lane & 15;          // 16 lanes x uint4 = 256 B row

    int beg = offsets[wid];
    int end = offsets[wid + 1];
    int count = end - beg;
    int cnt64 = (count < 64) ? count : 64;

    int2 myrec = make_int2(0, 0);             // pad: row 0, scale 0
    if (lane < cnt64) myrec = recs[beg + lane];

    float4 a0lo = {0.f,0.f,0.f,0.f}, a0hi = {0.f,0.f,0.f,0.f};
    float4 a1lo = {0.f,0.f,0.f,0.f}, a1hi = {0.f,0.f,0.f,0.f};
    float4 a2lo = {0.f,0.f,0.f,0.f}, a2hi = {0.f,0.f,0.f,0.f};

    for (int j = 0; j < cnt64; j += 4) {
        int srcl = j + qt;                    // <= 63 always (j <= 60)
        int rx = __shfl(myrec.x, srcl);
        int ry = __shfl(myrec.y, srcl);
        accum4(rx, ry, l16, xb, a0lo, a0hi, a1lo, a1hi, a2lo, a2hi);
    }
    for (int q = 64; q < count; q += 4) {     // rare high-degree tail
        int qq = q + qt;
        int rx = 0, ry = 0;
        if (qq < count) { int2 rec = recs[beg + qq]; rx = rec.x; ry = rec.y; }
        accum4(rx, ry, l16, xb, a0lo, a0hi, a1lo, a1hi, a2lo, a2hi);
    }

    // reduce partial sums across the 4 lane quarters
    red4(a0lo); red4(a0hi); red4(a1lo); red4(a1hi); red4(a2lo); red4(a2hi);

    // rotation neighbors (all lanes active for the shuffles)
    int prev = (l16 + 15) & 15;
    float a1p7 = __shfl(a1hi.w, prev);   // a1[8q-1]
    float a2p6 = __shfl(a2hi.z, prev);   // a2[8q-2]
    float a2p7 = __shfl(a2hi.w, prev);   // a2[8q-1]

    if (lane < 16) {
        const float4* xr = (const float4*)(x + (size_t)wid * D);
        float4 xlo = xr[2 * l16];
        float4 xhi = xr[2 * l16 + 1];
        // out[c] = r0*x[c] + a0[c] + a1[(c-1)&127] + a2[(c-2)&127]
        float4 olo, ohi;
        olo.x = r0 * xlo.x + a0lo.x + a1p7   + a2p6;
        olo.y = r0 * xlo.y + a0lo.y + a1lo.x + a2p7;
        olo.z = r0 * xlo.z + a0lo.z + a1lo.y + a2lo.x;
        olo.w = r0 * xlo.w + a0lo.w + a1lo.z + a2lo.y;
        ohi.x = r0 * xhi.x + a0hi.x + a1lo.w + a2lo.z;
        ohi.y = r0 * xhi.y + a0hi.y + a1hi.x + a2lo.w;
        ohi.z = r0 * xhi.z + a0hi.z + a1hi.y + a2hi.x;
        ohi.w = r0 * xhi.w + a0hi.w + a1hi.z + a2hi.y;
        float4* op = (float4*)(out + (size_t)wid * D);
        op[2 * l16]     = olo;
        op[2 * l16 + 1] = ohi;
    }
}

// overflow cleanup: wave per record, atomic add (expected ~0 records)
__global__ void ovf_kernel(const float* __restrict__ x,
                           const int* __restrict__ ovf_count,
                           const int4* __restrict__ ovf,
                           float* __restrict__ out) {
    int total_waves = (gridDim.x * blockDim.x) >> 6;
    int gw   = (blockIdx.x * blockDim.x + threadIdx.x) >> 6;
    int lane = threadIdx.x & 63;
    int n = *ovf_count;
    if (n > OVF_CAP) n = OVF_CAP;
    for (int r = gw; r < n; r += total_waves) {
        int4 rec = ovf[r];
        int src = rec.x;
        int dst = rec.y & 0x1FFFF;
        int sh  = (rec.y >> 17) & 3;
        float sc = __int_as_float(rec.z);
        const float* xr = x + (size_t)dst * D;
        float* orow = out + (size_t)src * D;
        int c0 = 2 * lane, c1 = 2 * lane + 1;
        atomicAdd(&orow[c0], sc * xr[(c0 - sh) & 127]);
        atomicAdd(&orow[c1], sc * xr[(c1 - sh) & 127]);
    }
}

// ===========================================================================
// MID TIER fallback (R3 exact-CSR path, fp32 gather), if ws too small.
// ===========================================================================
#define SCAN_BLOCKS ((N_NODES + 255) / 256)   // 391
#define WS_COUNTS   0
#define WS_OFFSETS  400000
#define WS_CURSORS  800008
#define WS_BSUM     1200008
#define WS_BPRE     1201576
#define WS_RECS     1203144
#define WS_NEEDED_MID (WS_RECS + (size_t)TOT_EDGES * 8)

__global__ void hist_kernel(const int* __restrict__ ei1, const int* __restrict__ ei2,
                            const int* __restrict__ ei3, int* __restrict__ counts) {
    int e = blockIdx.x * blockDim.x + threadIdx.x;
    if (e >= TOT_EDGES) return;
    int set = e / N_EDGES;
    int idx = e - set * N_EDGES;
    const int* ei = (set == 0) ? ei1 : (set == 1) ? ei2 : ei3;
    atomicAdd(&counts[ei[idx]], 1);
}

__global__ void scan1_kernel(const int* __restrict__ counts,
                             int* __restrict__ offsets, int* __restrict__ bsum) {
    __shared__ int s[256];
    int t = threadIdx.x;
    int i = blockIdx.x * 256 + t;
    int v = (i < N_NODES) ? counts[i] : 0;
    s[t] = v;
    __syncthreads();
    for (int off = 1; off < 256; off <<= 1) {
        int u = (t >= off) ? s[t - off] : 0;
        __syncthreads();
        s[t] += u;
        __syncthreads();
    }
    if (i < N_NODES) offsets[i] = s[t] - v;
    if (t == 255) bsum[blockIdx.x] = s[255];
}

__global__ void scan2_kernel(const int* __restrict__ bsum, int* __restrict__ bpre) {
    __shared__ int s[512];
    int t = threadIdx.x;
    int v = (t < SCAN_BLOCKS) ? bsum[t] : 0;
    s[t] = v;
    __syncthreads();
    for (int off = 1; off < 512; off <<= 1) {
        int u = (t >= off) ? s[t - off] : 0;
        __syncthreads();
        s[t] += u;
        __syncthreads();
    }
    if (t < SCAN_BLOCKS) bpre[t] = s[t] - v;
}

__global__ void scan3_kernel(int* __restrict__ offsets, const int* __restrict__ bpre,
                             int* __restrict__ cursors) {
    int i = blockIdx.x * 256 + threadIdx.x;
    if (i < N_NODES) {
        int v = offsets[i] + bpre[blockIdx.x];
        offsets[i] = v;
        cursors[i] = v;
    }
    if (i == 0) offsets[N_NODES] = TOT_EDGES;
}

__global__ void fill_kernel(const int* __restrict__ ei1, const float* __restrict__ w1,
                            const int* __restrict__ ei2, const float* __restrict__ w2,
                            const int* __restrict__ ei3, const float* __restrict__ w3,
                            const float* __restrict__ z0, const float* __restrict__ z1,
                            const float* __restrict__ z2, const float* __restrict__ z3,
                            int* __restrict__ cursors, int2* __restrict__ recs) {
    int e = blockIdx.x * blockDim.x + threadIdx.x;
    if (e >= TOT_EDGES) return;
    int set = e / N_EDGES;
    int idx = e - set * N_EDGES;
    const int* ei;  const float* w;
    if      (set == 0) { ei = ei1; w = w1; }
    else if (set == 1) { ei = ei2; w = w2; }
    else               { ei = ei3; w = w3; }
    float r0, r1, r2, r3;
    load_r(z0, z1, z2, z3, r0, r1, r2, r3);
    float rk = (set == 0) ? r1 : (set == 1) ? r2 : r3;
    int src = ei[idx];
    int dst = ei[N_EDGES + idx];
    float scale = rk * w[idx];
    int pos = atomicAdd(&cursors[src], 1);
    recs[pos] = make_int2(dst | (set << 17), __float_as_int(scale));
}

__global__ void gatherd_kernel(const float* __restrict__ x,
                               const int* __restrict__ offsets,
                               const int2* __restrict__ recs,
                               const float* __restrict__ z0, const float* __restrict__ z1,
                               const float* __restrict__ z2, const float* __restrict__ z3,
                               float* __restrict__ out) {
    int wid  = (blockIdx.x * blockDim.x + threadIdx.x) >> 6;
    int lane = threadIdx.x & 63;
    if (wid >= N_NODES) return;
    float r0, r1, r2, r3;
    load_r(z0, z1, z2, z3, r0, r1, r2, r3);
    float2 xv = ((const float2*)(x + (size_t)wid * D))[lane];
    int beg = offsets[wid];
    int end = offsets[wid + 1];
    float2 a0 = {0.f, 0.f}, a1 = {0.f, 0.f}, a2 = {0.f, 0.f};
    for (int j = beg; j < end; ++j) {
        int2 rec = recs[j];
        float2 v = ((const float2*)(x + (size_t)(rec.x & 0x1FFFF) * D))[lane];
        int sh = (rec.x >> 17) & 3;
        float sc = __int_as_float(rec.y);
        if      (sh == 0) { a0.x += sc * v.x; a0.y += sc * v.y; }
        else if (sh == 1) { a1.x += sc * v.x; a1.y += sc * v.y; }
        else               { a2.x += sc * v.x; a2.y += sc * v.y; }
    }
    int prev = (lane + 63) & 63;
    float r1y = __shfl(a1.y, prev);
    float r2x = __shfl(a2.x, prev);
    float r2y = __shfl(a2.y, prev);
    float2 o;
    o.x = r0 * xv.x + a0.x + r1y  + r2x;
    o.y = r0 * xv.y + a0.y + a1.x + r2y;
    ((float2*)(out + (size_t)wid * D))[lane] = o;
}

extern "C" void kernel_launch(void* const* d_in, const int* in_sizes, int n_in,
                              void* d_out, int out_size, void* d_ws, size_t ws_size,
                              hipStream_t stream) {
    const float* x   = (const float*)d_in[0];
    const int*   ei1 = (const int*)  d_in[1];
    const float* w1  = (const float*)d_in[2];
    const int*   ei2 = (const int*)  d_in[3];
    const float* w2  = (const float*)d_in[4];
    const int*   ei3 = (const int*)  d_in[5];
    const float* w3  = (const float*)d_in[6];
    const float* z0  = (const float*)d_in[7];
    const float* z1  = (const float*)d_in[8];
    const float* z2  = (const float*)d_in[9];
    const float* z3  = (const float*)d_in[10];
    float* out = (float*)d_out;
    char* wsc = (char*)d_ws;

    if (ws_size >= WS_TOTAL_FAST) {
        int*    ovf_count = (int*)   (wsc + WS_OVFCNT);
        int*    bcur      = (int*)   (wsc + WS_BCUR);
        int*    bbase     = (int*)   (wsc + WS_BBASE);
        int*    bnum      = (int*)   (wsc + WS_BNUM);
        int4*   ovf       = (int4*)  (wsc + WS_OVF);
        int2*   tmp       = (int2*)  (wsc + WS_TMP);
        int2*   frecs     = (int2*)  (wsc + WS_FREC);
        int*    offsets   = (int*)   (wsc + WS_OFFS);
        ushort* xb        = (ushort*)(wsc + WS_XB);

        hipMemsetAsync(wsc, 0, WS_BBASE, stream);   // ovf_count + bucket cursors
        cast_kernel<<<(N_NODES * D / 4 + 255) / 256, 256, 0, stream>>>(x, xb);
        binA_kernel<<<BINA_BLOCKS, 256, 0, stream>>>(ei1, w1, ei2, w2, ei3, w3,
                                                     z0, z1, z2, z3,
                                                     bcur, ovf_count, ovf, tmp);
        scanB_kernel<<<1, NB, 0, stream>>>(bcur, bbase, bnum, offsets);
        binB_kernel<<<NB, 256, 0, stream>>>(tmp, bbase, bnum, frecs, offsets);
        gatherb_kernel<<<(N_NODES * 64 + 255) / 256, 256, 0, stream>>>(x, xb, offsets,
                                                                       frecs, z0, z1, z2, z3,
                                                                       out);
        ovf_kernel<<<128, 256, 0, stream>>>(x, ovf_count, ovf, out);
    } else {
        int*  counts  = (int*) (wsc + WS_COUNTS);
        int*  offsets = (int*) (wsc + WS_OFFSETS);
        int*  cursors = (int*) (wsc + WS_CURSORS);
        int*  bsum    = (int*) (wsc + WS_BSUM);
        int*  bpre    = (int*) (wsc + WS_BPRE);
        int2* recs    = (int2*)(wsc + WS_RECS);

        hipMemsetAsync(counts, 0, N_NODES * sizeof(int), stream);
        hist_kernel<<<TOT_EDGES / 256, 256, 0, stream>>>(ei1, ei2, ei3, counts);
        scan1_kernel<<<SCAN_BLOCKS, 256, 0, stream>>>(counts, offsets, bsum);
        scan2_kernel<<<1, 512, 0, stream>>>(bsum, bpre);
        scan3_kernel<<<SCAN_BLOCKS, 256, 0, stream>>>(offsets, bpre, cursors);
        fill_kernel<<<TOT_EDGES / 256, 256, 0, stream>>>(ei1, w1, ei2, w2, ei3, w3,
                                                         z0, z1, z2, z3, cursors, recs);
        gatherd_kernel<<<(N_NODES * 64 + 255) / 256, 256, 0, stream>>>(x, offsets, recs,
                                                                       z0, z1, z2, z3, out);
    }
}

// Round 2
// 280.260 us; speedup vs baseline: 2.0761x; 2.0761x over previous
//
#include <hip/hip_runtime.h>

#define N_NODES 100000
#define D 128
#define N_EDGES 640000
#define TOT_EDGES (3 * N_EDGES)   // 1,920,000

#define NB   256                  // buckets (node ranges)
#define NPB  391                  // nodes per bucket (256*391 >= 100000)
#define BCAP 9216                 // record capacity per bucket (mean 7500, +20 sigma)
#define OVF_CAP 16384
#define EPB  3072                 // edges per binA block
#define BINA_BLOCKS (TOT_EDGES / EPB)   // 625
#define EPT  (EPB / 256)                // 12 edges per thread
#define NKEY 2048                 // pow2 >= NPB*4 (local*4+set sort key space)

// ---------------- fast-path ws layout (bytes); total 60,515,016 ------------
#define WS_OVFCNT 0
#define WS_BCUR   64                         // int, stride 16 ints (64B/bucket)
#define WS_BBASE  16448                      // int[256]
#define WS_BNUM   17472                      // int[256]
#define WS_OVF    18496                      // int4[OVF_CAP], 256 KB
#define WS_TMP    280640                     // int2[NB*BCAP], 18.87 MB
#define WS_FREC   19155008                   // int2[TOT_EDGES], 15.36 MB
#define WS_OFFS   34515008                   // int[N_NODES+1]
#define WS_XB     34915016                   // ushort[N_NODES*D] bf16, 25.6 MB
#define WS_TOTAL_FAST 60515016

#ifndef __has_builtin
#define __has_builtin(x) 0
#endif
#if __has_builtin(__builtin_amdgcn_alignbit)
#define ALIGN16(hi, lo) __builtin_amdgcn_alignbit((hi), (lo), 16)
#else
#define ALIGN16(hi, lo) (((hi) << 16) | ((lo) >> 16))
#endif

__device__ __forceinline__ void load_r(const float* z0, const float* z1,
                                       const float* z2, const float* z3,
                                       float& r0, float& r1, float& r2, float& r3) {
    r0 = fmaxf(z0[0], 0.0f);
    r1 = fmaxf(z1[0], 0.0f);
    r2 = fmaxf(z2[0], 0.0f);
    r3 = fmaxf(z3[0], 0.0f);
    float inv = 1.0f / (r0 + r1 + r2 + r3 + 1e-6f);
    r0 *= inv; r1 *= inv; r2 *= inv; r3 *= inv;
}

__device__ __forceinline__ unsigned short bf16rn(float f) {
    unsigned int u = __float_as_uint(f);
    u += 0x7FFFu + ((u >> 16) & 1u);   // round to nearest even
    return (unsigned short)(u >> 16);
}

// ---- cast x -> bf16 copy (halves gather traffic) ---------------------------
__global__ void cast_kernel(const float* __restrict__ x, ushort* __restrict__ xb) {
    int i = blockIdx.x * 256 + threadIdx.x;
    if (i >= N_NODES * D / 4) return;
    float4 v = ((const float4*)x)[i];
    ushort4 h;
    h.x = bf16rn(v.x); h.y = bf16rn(v.y); h.z = bf16rn(v.z); h.w = bf16rn(v.w);
    ((ushort4*)xb)[i] = h;
}

// ---------------------------------------------------------------------------
// binA: LDS-aggregated binning of all edges into 256 node-range buckets.
// Single pass over edge arrays; record built in registers.
// tmp rec: x = dst(17) | set<<17 (2) | local<<19 (9), y = f32 scale.
// ---------------------------------------------------------------------------
__global__ void binA_kernel(const int* __restrict__ ei1, const float* __restrict__ w1,
                            const int* __restrict__ ei2, const float* __restrict__ w2,
                            const int* __restrict__ ei3, const float* __restrict__ w3,
                            const float* __restrict__ z0, const float* __restrict__ z1,
                            const float* __restrict__ z2, const float* __restrict__ z3,
                            int* __restrict__ bcur, int* __restrict__ ovf_count,
                            int4* __restrict__ ovf, int2* __restrict__ tmp) {
    __shared__ int hist[NB];
    __shared__ int base[NB];
    int t = threadIdx.x;
    hist[t] = 0;
    __syncthreads();

    float r0, r1, r2, r3;
    load_r(z0, z1, z2, z3, r0, r1, r2, r3);

    int e0 = blockIdx.x * EPB;
    int rank[EPT];
    int bkt[EPT];
    int rxv[EPT];
    float scv[EPT];

#pragma unroll
    for (int k = 0; k < EPT; ++k) {
        int e = e0 + t + k * 256;
        int set = e / N_EDGES;
        int idx = e - set * N_EDGES;
        const int* ei;  const float* w;  float rk;
        if      (set == 0) { ei = ei1; w = w1; rk = r1; }
        else if (set == 1) { ei = ei2; w = w2; rk = r2; }
        else               { ei = ei3; w = w3; rk = r3; }
        int src = ei[idx];
        int dst = ei[N_EDGES + idx];
        int b = src / NPB;
        int local = src - b * NPB;
        bkt[k]  = b;
        rxv[k]  = dst | (set << 17) | (local << 19);
        scv[k]  = rk * w[idx];
        rank[k] = atomicAdd(&hist[b], 1);
    }
    __syncthreads();

    {
        int h = hist[t];
        base[t] = h ? atomicAdd(&bcur[t * 16], h) : 0;
    }
    __syncthreads();

#pragma unroll
    for (int k = 0; k < EPT; ++k) {
        int b = bkt[k];
        int pos = base[b] + rank[k];
        if (pos < BCAP) {
            tmp[(size_t)b * BCAP + pos] = make_int2(rxv[k], __float_as_int(scv[k]));
        } else {
            int o = atomicAdd(ovf_count, 1);
            int src = b * NPB + ((rxv[k] >> 19) & 0x1FF);
            if (o < OVF_CAP) ovf[o] = make_int4(src, rxv[k] & 0x7FFFF,
                                                __float_as_int(scv[k]), 0);
        }
    }
}

// scanB: exclusive scan of (clamped) bucket counts -> global bucket bases.
__global__ void scanB_kernel(const int* __restrict__ bcur,
                             int* __restrict__ bbase, int* __restrict__ bnum,
                             int* __restrict__ offsets) {
    __shared__ int s[NB];
    int t = threadIdx.x;
    int n = bcur[t * 16];
    if (n > BCAP) n = BCAP;
    bnum[t] = n;
    s[t] = n;
    __syncthreads();
    for (int off = 1; off < NB; off <<= 1) {
        int v = (t >= off) ? s[t - off] : 0;
        __syncthreads();
        s[t] += v;
        __syncthreads();
    }
    bbase[t] = s[t] - n;
    if (t == NB - 1) offsets[N_NODES] = s[t];
}

// binB: per-bucket local CSR via counting sort on key = local*4 + set.
__global__ void binB_kernel(const int2* __restrict__ tmp,
                            const int* __restrict__ bbase, const int* __restrict__ bnum,
                            int2* __restrict__ frecs, int* __restrict__ offsets) {
    __shared__ int d[NKEY];
    __shared__ int ts[256];
    __shared__ int cur[NKEY];
    int b = blockIdx.x;
    int t = threadIdx.x;
    int n = bnum[b];
    int gbase = bbase[b];

    for (int i = t; i < NKEY; i += 256) d[i] = 0;
    __syncthreads();
    for (int i = t; i < n; i += 256) {
        int rx = tmp[(size_t)b * BCAP + i].x;
        int key = (((rx >> 19) & 0x1FF) << 2) | ((rx >> 17) & 3);
        atomicAdd(&d[key], 1);
    }
    __syncthreads();

    // scan: thread t owns keys 8t..8t+7 (serial) + 256-wide block scan
    int loc[8];
    int tot = 0;
#pragma unroll
    for (int k = 0; k < 8; ++k) { loc[k] = tot; tot += d[8 * t + k]; }
    ts[t] = tot;
    __syncthreads();
    for (int off = 1; off < 256; off <<= 1) {
        int v = (t >= off) ? ts[t - off] : 0;
        __syncthreads();
        ts[t] += v;
        __syncthreads();
    }
    int tbase = ts[t] - tot;
#pragma unroll
    for (int k = 0; k < 8; ++k) cur[8 * t + k] = tbase + loc[k];
    __syncthreads();

    int node0 = b * NPB;
    for (int l = t; l < NPB; l += 256) {
        int node = node0 + l;
        if (node < N_NODES) offsets[node] = gbase + cur[l << 2];
    }
    __syncthreads();

    for (int i = t; i < n; i += 256) {
        int2 rec = tmp[(size_t)b * BCAP + i];
        int key = (((rec.x >> 19) & 0x1FF) << 2) | ((rec.x >> 17) & 3);
        int pos = atomicAdd(&cur[key], 1);
        frecs[gbase + pos] = make_int2(rec.x & 0x7FFFF, rec.y);
    }
}

// ---------------------------------------------------------------------------
// gatherb v3: wave per node; 4 records per round, each row read by one 16-lane
// quarter as uint4 (16B/lane). Rotation applied at load time via packed
// bf16x2 word shift (shfl prev-lane + alignbit + 2 cndmask/word), so there is
// ONE set of 8 scalar accumulators — all named scalars, no aggregates, no
// helper-by-reference (v2's scratch-spill killer).
// ---------------------------------------------------------------------------
#define GB_ACCUM(RX, RY)                                                       \
    {                                                                          \
        const uint4* rowp = (const uint4*)(xb + (size_t)((RX) & 0x1FFFF) * D); \
        uint4 v = rowp[l16];                                                   \
        int sh = ((RX) >> 17) & 3;                                             \
        float sc = __int_as_float(RY);                                         \
        unsigned int pw = (unsigned int)__shfl((int)v.w, prevq);               \
        unsigned int s1x = ALIGN16(v.x, pw);                                   \
        unsigned int s1y = ALIGN16(v.y, v.x);                                  \
        unsigned int s1z = ALIGN16(v.z, v.y);                                  \
        unsigned int s1w = ALIGN16(v.w, v.z);                                  \
        unsigned int u0 = (sh == 0) ? v.x : (sh == 1) ? s1x : pw;              \
        unsigned int u1 = (sh == 0) ? v.y : (sh == 1) ? s1y : v.x;             \
        unsigned int u2 = (sh == 0) ? v.z : (sh == 1) ? s1z : v.y;             \
        unsigned int u3 = (sh == 0) ? v.w : (sh == 1) ? s1w : v.z;             \
        acc0 += sc * __uint_as_float(u0 << 16);                                \
        acc1 += sc * __uint_as_float(u0 & 0xFFFF0000u);                        \
        acc2 += sc * __uint_as_float(u1 << 16);                                \
        acc3 += sc * __uint_as_float(u1 & 0xFFFF0000u);                        \
        acc4 += sc * __uint_as_float(u2 << 16);                                \
        acc5 += sc * __uint_as_float(u2 & 0xFFFF0000u);                        \
        acc6 += sc * __uint_as_float(u3 << 16);                                \
        acc7 += sc * __uint_as_float(u3 & 0xFFFF0000u);                        \
    }

__global__ void gatherb_kernel(const float* __restrict__ x,
                               const ushort* __restrict__ xb,
                               const int* __restrict__ offsets,
                               const int2* __restrict__ recs,
                               const float* __restrict__ z0, const float* __restrict__ z1,
                               const float* __restrict__ z2, const float* __restrict__ z3,
                               float* __restrict__ out) {
    int wid  = (blockIdx.x * blockDim.x + threadIdx.x) >> 6;
    int lane = threadIdx.x & 63;
    if (wid >= N_NODES) return;

    float r0, r1, r2, r3;
    load_r(z0, z1, z2, z3, r0, r1, r2, r3);

    int qt    = lane >> 4;                    // record slot within 4-group
    int l16   = lane & 15;                    // 16 lanes x uint4 = 256 B row
    int prevq = (qt << 4) | ((l16 + 15) & 15);

    int beg = offsets[wid];
    int end = offsets[wid + 1];
    int count = end - beg;
    int cnt64 = (count < 64) ? count : 64;

    int mrx = 0, mry = 0;                     // pad: row 0, scale 0
    if (lane < cnt64) { int2 rec = recs[beg + lane]; mrx = rec.x; mry = rec.y; }

    float acc0 = 0.f, acc1 = 0.f, acc2 = 0.f, acc3 = 0.f;
    float acc4 = 0.f, acc5 = 0.f, acc6 = 0.f, acc7 = 0.f;

    for (int j = 0; j < cnt64; j += 4) {
        int srcl = j + qt;                    // <= 63 always (j <= 60)
        int rx = __shfl(mrx, srcl);
        int ry = __shfl(mry, srcl);
        GB_ACCUM(rx, ry)
    }
    for (int q = 64; q < count; q += 4) {     // rare high-degree tail
        int qq = q + qt;
        int rx = 0, ry = 0;
        if (qq < count) { int2 rec = recs[beg + qq]; rx = rec.x; ry = rec.y; }
        GB_ACCUM(rx, ry)
    }

    // reduce partial sums across the 4 lane quarters
    acc0 += __shfl_xor(acc0, 16); acc0 += __shfl_xor(acc0, 32);
    acc1 += __shfl_xor(acc1, 16); acc1 += __shfl_xor(acc1, 32);
    acc2 += __shfl_xor(acc2, 16); acc2 += __shfl_xor(acc2, 32);
    acc3 += __shfl_xor(acc3, 16); acc3 += __shfl_xor(acc3, 32);
    acc4 += __shfl_xor(acc4, 16); acc4 += __shfl_xor(acc4, 32);
    acc5 += __shfl_xor(acc5, 16); acc5 += __shfl_xor(acc5, 32);
    acc6 += __shfl_xor(acc6, 16); acc6 += __shfl_xor(acc6, 32);
    acc7 += __shfl_xor(acc7, 16); acc7 += __shfl_xor(acc7, 32);

    if (lane < 16) {
        const float4* xr = (const float4*)(x + (size_t)wid * D);
        float4 xlo = xr[2 * l16];
        float4 xhi = xr[2 * l16 + 1];
        float4 olo, ohi;
        olo.x = r0 * xlo.x + acc0;
        olo.y = r0 * xlo.y + acc1;
        olo.z = r0 * xlo.z + acc2;
        olo.w = r0 * xlo.w + acc3;
        ohi.x = r0 * xhi.x + acc4;
        ohi.y = r0 * xhi.y + acc5;
        ohi.z = r0 * xhi.z + acc6;
        ohi.w = r0 * xhi.w + acc7;
        float4* op = (float4*)(out + (size_t)wid * D);
        op[2 * l16]     = olo;
        op[2 * l16 + 1] = ohi;
    }
}

// overflow cleanup: wave per record, atomic add (expected ~0 records)
__global__ void ovf_kernel(const float* __restrict__ x,
                           const int* __restrict__ ovf_count,
                           const int4* __restrict__ ovf,
                           float* __restrict__ out) {
    int total_waves = (gridDim.x * blockDim.x) >> 6;
    int gw   = (blockIdx.x * blockDim.x + threadIdx.x) >> 6;
    int lane = threadIdx.x & 63;
    int n = *ovf_count;
    if (n > OVF_CAP) n = OVF_CAP;
    for (int r = gw; r < n; r += total_waves) {
        int4 rec = ovf[r];
        int src = rec.x;
        int dst = rec.y & 0x1FFFF;
        int sh  = (rec.y >> 17) & 3;
        float sc = __int_as_float(rec.z);
        const float* xr = x + (size_t)dst * D;
        float* orow = out + (size_t)src * D;
        int c0 = 2 * lane, c1 = 2 * lane + 1;
        atomicAdd(&orow[c0], sc * xr[(c0 - sh) & 127]);
        atomicAdd(&orow[c1], sc * xr[(c1 - sh) & 127]);
    }
}

// ===========================================================================
// MID TIER fallback (R3 exact-CSR path, fp32 gather), if ws too small.
// ===========================================================================
#define SCAN_BLOCKS ((N_NODES + 255) / 256)   // 391
#define WS_COUNTS   0
#define WS_OFFSETS  400000
#define WS_CURSORS  800008
#define WS_BSUM     1200008
#define WS_BPRE     1201576
#define WS_RECS     1203144
#define WS_NEEDED_MID (WS_RECS + (size_t)TOT_EDGES * 8)

__global__ void hist_kernel(const int* __restrict__ ei1, const int* __restrict__ ei2,
                            const int* __restrict__ ei3, int* __restrict__ counts) {
    int e = blockIdx.x * blockDim.x + threadIdx.x;
    if (e >= TOT_EDGES) return;
    int set = e / N_EDGES;
    int idx = e - set * N_EDGES;
    const int* ei = (set == 0) ? ei1 : (set == 1) ? ei2 : ei3;
    atomicAdd(&counts[ei[idx]], 1);
}

__global__ void scan1_kernel(const int* __restrict__ counts,
                             int* __restrict__ offsets, int* __restrict__ bsum) {
    __shared__ int s[256];
    int t = threadIdx.x;
    int i = blockIdx.x * 256 + t;
    int v = (i < N_NODES) ? counts[i] : 0;
    s[t] = v;
    __syncthreads();
    for (int off = 1; off < 256; off <<= 1) {
        int u = (t >= off) ? s[t - off] : 0;
        __syncthreads();
        s[t] += u;
        __syncthreads();
    }
    if (i < N_NODES) offsets[i] = s[t] - v;
    if (t == 255) bsum[blockIdx.x] = s[255];
}

__global__ void scan2_kernel(const int* __restrict__ bsum, int* __restrict__ bpre) {
    __shared__ int s[512];
    int t = threadIdx.x;
    int v = (t < SCAN_BLOCKS) ? bsum[t] : 0;
    s[t] = v;
    __syncthreads();
    for (int off = 1; off < 512; off <<= 1) {
        int u = (t >= off) ? s[t - off] : 0;
        __syncthreads();
        s[t] += u;
        __syncthreads();
    }
    if (t < SCAN_BLOCKS) bpre[t] = s[t] - v;
}

__global__ void scan3_kernel(int* __restrict__ offsets, const int* __restrict__ bpre,
                             int* __restrict__ cursors) {
    int i = blockIdx.x * 256 + threadIdx.x;
    if (i < N_NODES) {
        int v = offsets[i] + bpre[blockIdx.x];
        offsets[i] = v;
        cursors[i] = v;
    }
    if (i == 0) offsets[N_NODES] = TOT_EDGES;
}

__global__ void fill_kernel(const int* __restrict__ ei1, const float* __restrict__ w1,
                            const int* __restrict__ ei2, const float* __restrict__ w2,
                            const int* __restrict__ ei3, const float* __restrict__ w3,
                            const float* __restrict__ z0, const float* __restrict__ z1,
                            const float* __restrict__ z2, const float* __restrict__ z3,
                            int* __restrict__ cursors, int2* __restrict__ recs) {
    int e = blockIdx.x * blockDim.x + threadIdx.x;
    if (e >= TOT_EDGES) return;
    int set = e / N_EDGES;
    int idx = e - set * N_EDGES;
    const int* ei;  const float* w;
    if      (set == 0) { ei = ei1; w = w1; }
    else if (set == 1) { ei = ei2; w = w2; }
    else               { ei = ei3; w = w3; }
    float r0, r1, r2, r3;
    load_r(z0, z1, z2, z3, r0, r1, r2, r3);
    float rk = (set == 0) ? r1 : (set == 1) ? r2 : r3;
    int src = ei[idx];
    int dst = ei[N_EDGES + idx];
    float scale = rk * w[idx];
    int pos = atomicAdd(&cursors[src], 1);
    recs[pos] = make_int2(dst | (set << 17), __float_as_int(scale));
}

__global__ void gatherd_kernel(const float* __restrict__ x,
                               const int* __restrict__ offsets,
                               const int2* __restrict__ recs,
                               const float* __restrict__ z0, const float* __restrict__ z1,
                               const float* __restrict__ z2, const float* __restrict__ z3,
                               float* __restrict__ out) {
    int wid  = (blockIdx.x * blockDim.x + threadIdx.x) >> 6;
    int lane = threadIdx.x & 63;
    if (wid >= N_NODES) return;
    float r0, r1, r2, r3;
    load_r(z0, z1, z2, z3, r0, r1, r2, r3);
    float2 xv = ((const float2*)(x + (size_t)wid * D))[lane];
    int beg = offsets[wid];
    int end = offsets[wid + 1];
    float2 a0 = {0.f, 0.f}, a1 = {0.f, 0.f}, a2 = {0.f, 0.f};
    for (int j = beg; j < end; ++j) {
        int2 rec = recs[j];
        float2 v = ((const float2*)(x + (size_t)(rec.x & 0x1FFFF) * D))[lane];
        int sh = (rec.x >> 17) & 3;
        float sc = __int_as_float(rec.y);
        if      (sh == 0) { a0.x += sc * v.x; a0.y += sc * v.y; }
        else if (sh == 1) { a1.x += sc * v.x; a1.y += sc * v.y; }
        else               { a2.x += sc * v.x; a2.y += sc * v.y; }
    }
    int prev = (lane + 63) & 63;
    float r1y = __shfl(a1.y, prev);
    float r2x = __shfl(a2.x, prev);
    float r2y = __shfl(a2.y, prev);
    float2 o;
    o.x = r0 * xv.x + a0.x + r1y  + r2x;
    o.y = r0 * xv.y + a0.y + a1.x + r2y;
    ((float2*)(out + (size_t)wid * D))[lane] = o;
}

extern "C" void kernel_launch(void* const* d_in, const int* in_sizes, int n_in,
                              void* d_out, int out_size, void* d_ws, size_t ws_size,
                              hipStream_t stream) {
    const float* x   = (const float*)d_in[0];
    const int*   ei1 = (const int*)  d_in[1];
    const float* w1  = (const float*)d_in[2];
    const int*   ei2 = (const int*)  d_in[3];
    const float* w2  = (const float*)d_in[4];
    const int*   ei3 = (const int*)  d_in[5];
    const float* w3  = (const float*)d_in[6];
    const float* z0  = (const float*)d_in[7];
    const float* z1  = (const float*)d_in[8];
    const float* z2  = (const float*)d_in[9];
    const float* z3  = (const float*)d_in[10];
    float* out = (float*)d_out;
    char* wsc = (char*)d_ws;

    if (ws_size >= WS_TOTAL_FAST) {
        int*    ovf_count = (int*)   (wsc + WS_OVFCNT);
        int*    bcur      = (int*)   (wsc + WS_BCUR);
        int*    bbase     = (int*)   (wsc + WS_BBASE);
        int*    bnum      = (int*)   (wsc + WS_BNUM);
        int4*   ovf       = (int4*)  (wsc + WS_OVF);
        int2*   tmp       = (int2*)  (wsc + WS_TMP);
        int2*   frecs     = (int2*)  (wsc + WS_FREC);
        int*    offsets   = (int*)   (wsc + WS_OFFS);
        ushort* xb        = (ushort*)(wsc + WS_XB);

        hipMemsetAsync(wsc, 0, WS_BBASE, stream);   // ovf_count + bucket cursors
        cast_kernel<<<(N_NODES * D / 4 + 255) / 256, 256, 0, stream>>>(x, xb);
        binA_kernel<<<BINA_BLOCKS, 256, 0, stream>>>(ei1, w1, ei2, w2, ei3, w3,
                                                     z0, z1, z2, z3,
                                                     bcur, ovf_count, ovf, tmp);
        scanB_kernel<<<1, NB, 0, stream>>>(bcur, bbase, bnum, offsets);
        binB_kernel<<<NB, 256, 0, stream>>>(tmp, bbase, bnum, frecs, offsets);
        gatherb_kernel<<<(N_NODES * 64 + 255) / 256, 256, 0, stream>>>(x, xb, offsets,
                                                                       frecs, z0, z1, z2, z3,
                                                                       out);
        ovf_kernel<<<128, 256, 0, stream>>>(x, ovf_count, ovf, out);
    } else {
        int*  counts  = (int*) (wsc + WS_COUNTS);
        int*  offsets = (int*) (wsc + WS_OFFSETS);
        int*  cursors = (int*) (wsc + WS_CURSORS);
        int*  bsum    = (int*) (wsc + WS_BSUM);
        int*  bpre    = (int*) (wsc + WS_BPRE);
        int2* recs    = (int2*)(wsc + WS_RECS);

        hipMemsetAsync(counts, 0, N_NODES * sizeof(int), stream);
        hist_kernel<<<TOT_EDGES / 256, 256, 0, stream>>>(ei1, ei2, ei3, counts);
        scan1_kernel<<<SCAN_BLOCKS, 256, 0, stream>>>(counts, offsets, bsum);
        scan2_kernel<<<1, 512, 0, stream>>>(bsum, bpre);
        scan3_kernel<<<SCAN_BLOCKS, 256, 0, stream>>>(offsets, bpre, cursors);
        fill_kernel<<<TOT_EDGES / 256, 256, 0, stream>>>(ei1, w1, ei2, w2, ei3, w3,
                                                         z0, z1, z2, z3, cursors, recs);
        gatherd_kernel<<<(N_NODES * 64 + 255) / 256, 256, 0, stream>>>(x, offsets, recs,
                                                                       z0, z1, z2, z3, out);
    }
}